// Round 4
// baseline (1780.807 us; speedup 1.0000x reference)
//
#include <hip/hip_runtime.h>
#include <math.h>

namespace {
constexpr int Bn = 8, Tn = 4096, Hn = 4, HVn = 8, Kn = 128, Vn = 128;
constexpr float SCALE = 0.088388347648318447f;  // 128^-0.5
}

typedef float f2 __attribute__((ext_vector_type(2)));
typedef float f4 __attribute__((ext_vector_type(4)));

// ---------------- DPP cross-lane add (VALU-class, no DS latency) ----------
// 0xB1 = quad_perm[1,0,3,2] (xor1), 0x4E = quad_perm[2,3,0,1] (xor2),
// 0x141 = row_half_mirror (i^7: xor4 substitute AFTER quads reduced),
// 0x140 = row_mirror (i^15: xor8 substitute AFTER 8-groups reduced).
template <int CTRL>
__device__ __forceinline__ float red_dpp(float x) {
  return x + __int_as_float(
      __builtin_amdgcn_mov_dpp(__float_as_int(x), CTRL, 0xF, 0xF, true));
}

// ---------------- pre-pass: per-(b,t) scalars ----------------
// S[(b*T+t)*HV + hv] = { eg, beta*rk, eg*rk, rq*SCALE }
__global__ __launch_bounds__(256) void gdn_prepass(
    const float* __restrict__ A_log, const float* __restrict__ a_in,
    const float* __restrict__ dt_bias, const float* __restrict__ q_in,
    const float* __restrict__ k_in, const float* __restrict__ b_in,
    float4* __restrict__ S)
{
  const int bt = blockIdx.x * 4 + (threadIdx.x >> 6);  // 4 bt per block
  const int lane = threadIdx.x & 63;
  const int h  = lane >> 4;           // 16 lanes per head
  const int j0 = (lane & 15) * 8;

  const float* kp = k_in + ((long)bt * Hn + h) * Kn + j0;
  const float* qp = q_in + ((long)bt * Hn + h) * Kn + j0;
  const float4 ka = *(const float4*)kp;
  const float4 kb = *(const float4*)(kp + 4);
  const float4 qa = *(const float4*)qp;
  const float4 qb = *(const float4*)(qp + 4);

  float ks = ka.x*ka.x + ka.y*ka.y + ka.z*ka.z + ka.w*ka.w
           + kb.x*kb.x + kb.y*kb.y + kb.z*kb.z + kb.w*kb.w;
  float qs = qa.x*qa.x + qa.y*qa.y + qa.z*qa.z + qa.w*qa.w
           + qb.x*qb.x + qb.y*qb.y + qb.z*qb.z + qb.w*qb.w;
  ks = red_dpp<0xB1>(ks);  qs = red_dpp<0xB1>(qs);
  ks = red_dpp<0x4E>(ks);  qs = red_dpp<0x4E>(qs);
  ks = red_dpp<0x141>(ks); qs = red_dpp<0x141>(qs);
  ks = red_dpp<0x140>(ks); qs = red_dpp<0x140>(qs);
  const float rk = rsqrtf(ks + 1e-6f);
  const float rq = rsqrtf(qs + 1e-6f);

  // lanes j<2 of row h handle hv = 2h+j directly (no cross-row shuffle)
  const int j = lane & 15;
  if (j < 2) {
    const int hv = 2 * h + j;
    const long sidx = (long)bt * HVn + hv;
    const float x  = a_in[sidx] + dt_bias[hv];
    const float sp = (x <= 20.0f) ? log1pf(expf(x)) : x;   // softplus
    const float eg = expf(-expf(A_log[hv]) * sp);
    const float beta = 1.0f / (1.0f + expf(-b_in[sidx]));
    S[sidx] = make_float4(eg, beta * rk, eg * rk, rq * SCALE);
  }
}

// ---------------- recurrent scan ----------------
// one recurrence step; 8 state rows x 1 col per lane, packed f32 math
__device__ __forceinline__ float core_step(f2 (&hs)[4],
    const f4 k0, const f4 k1, const f4 q0, const f4 q1,
    const float tv, const f4 ts)
{
  const f2 k0l = f2{k0.x,k0.y}, k0h = f2{k0.z,k0.w};
  const f2 k1l = f2{k1.x,k1.y}, k1h = f2{k1.z,k1.w};
  const f2 q0l = f2{q0.x,q0.y}, q0h = f2{q0.z,q0.w};
  const f2 q1l = f2{q1.x,q1.y}, q1h = f2{q1.z,q1.w};
  f2 d1 = f2{0.f,0.f}, d2 = f2{0.f,0.f}, d3 = f2{0.f,0.f};
  d1 = __builtin_elementwise_fma(hs[0], k0l, d1);
  d2 = __builtin_elementwise_fma(hs[0], q0l, d2);
  d3 = __builtin_elementwise_fma(k0l, q0l, d3);
  d1 = __builtin_elementwise_fma(hs[1], k0h, d1);
  d2 = __builtin_elementwise_fma(hs[1], q0h, d2);
  d3 = __builtin_elementwise_fma(k0h, q0h, d3);
  d1 = __builtin_elementwise_fma(hs[2], k1l, d1);
  d2 = __builtin_elementwise_fma(hs[2], q1l, d2);
  d3 = __builtin_elementwise_fma(k1l, q1l, d3);
  d1 = __builtin_elementwise_fma(hs[3], k1h, d1);
  d2 = __builtin_elementwise_fma(hs[3], q1h, d2);
  d3 = __builtin_elementwise_fma(k1h, q1h, d3);
  float s1 = d1.x + d1.y, s2 = d2.x + d2.y, s3 = d3.x + d3.y;
  // reduce over kk = lane&15: 4 all-DPP rounds, no DS ops on the chain
  s1 = red_dpp<0xB1>(s1);  s2 = red_dpp<0xB1>(s2);  s3 = red_dpp<0xB1>(s3);
  s1 = red_dpp<0x4E>(s1);  s2 = red_dpp<0x4E>(s2);  s3 = red_dpp<0x4E>(s3);
  s1 = red_dpp<0x141>(s1); s2 = red_dpp<0x141>(s2); s3 = red_dpp<0x141>(s3);
  s1 = red_dpp<0x140>(s1); s2 = red_dpp<0x140>(s2); s3 = red_dpp<0x140>(s3);
  const float c1 = ts.x;
  const float up = (tv - ts.z * s1) * ts.y;        // rk * u
  const float o  = fmaf(c1, s2, up * s3) * ts.w;   // (eg*d2 + u'*d3) * rq*scale
  const f2 c1v = f2{c1, c1}, upv = f2{up, up};
  hs[0] = __builtin_elementwise_fma(k0l, upv, hs[0] * c1v);
  hs[1] = __builtin_elementwise_fma(k0h, upv, hs[1] * c1v);
  hs[2] = __builtin_elementwise_fma(k1l, upv, hs[2] * c1v);
  hs[3] = __builtin_elementwise_fma(k1h, upv, hs[3] * c1v);
  return o;
}

// 2048 blocks = 64 (b,hv) x 32 v-splits; 1 wave/block; 8 blocks/CU (2/SIMD).
// Lane layout: kk = lane&15 (8 k-rows each), vv = lane>>4 (1 v-col).
// NO LDS. All loop VMEM is inline asm with hand-counted vmcnt: 4-deep
// rotating register prefetch (6 loads + 1 masked store per step).
__global__ __launch_bounds__(64, 2) void gdn_recurrent(
    const float* __restrict__ q_in, const float* __restrict__ k_in,
    const float* __restrict__ v_in, const float4* __restrict__ S,
    const float* __restrict__ h0_src, const int* __restrict__ h0_idx,
    float* __restrict__ out)
{
  const int blk  = blockIdx.x;
  const int g    = blk & 63;       // 32 v-split sharers of (b,hv) share an XCD
  const int vblk = blk >> 6;       // [0,32)
  const int b  = g >> 3;
  const int hv = g & 7;
  const int h  = hv >> 1;          // GQA rep=2
  const int lane = threadIdx.x;
  const int kk  = lane & 15;
  const int vv  = lane >> 4;
  const int vg  = vblk * 4 + vv;
  const int kk4 = kk * 4;

  const float* kbp = k_in + ((long)b * Tn * Hn + h) * Kn;
  const float* qbp = q_in + ((long)b * Tn * Hn + h) * Kn;
  const float* vbp = v_in + ((long)b * Tn * HVn + hv) * Vn;
  const f4*    sbp = ((const f4*)S) + (long)b * Tn * HVn + hv;
  const float* obp = out + ((long)b * Tn * HVn + hv) * Vn;
  const unsigned long long STMASK = 0x0001000100010001ULL;  // lanes 0,16,32,48

  unsigned voKQ = (unsigned)(kk * 16);  // + t*2048  (k and q share layout)
  unsigned voV  = (unsigned)(vg * 4);   // + t*4096
  unsigned voS  = 0u;                   // + t*128
  unsigned voO  = (unsigned)(vg * 4);   // + t*4096

  // state: 8 rows x 1 col per lane; rows {i*64 + kk*4 + m}
  f2 hs[4];
  {
    const int idx = h0_idx[b];
    if (idx >= 0) {
      const float* hp = h0_src + (((long)idx * HVn + hv) * Kn) * Vn + vg;
      hs[0] = f2{hp[(kk4+0)*Vn],    hp[(kk4+1)*Vn]};
      hs[1] = f2{hp[(kk4+2)*Vn],    hp[(kk4+3)*Vn]};
      hs[2] = f2{hp[(64+kk4+0)*Vn], hp[(64+kk4+1)*Vn]};
      hs[3] = f2{hp[(64+kk4+2)*Vn], hp[(64+kk4+3)*Vn]};
    } else {
      hs[0] = hs[1] = hs[2] = hs[3] = f2{0.f, 0.f};
    }
  }
  // drain compiler vmem so the asm vmcnt stream starts empty
  asm volatile("s_waitcnt vmcnt(0)" ::: "memory");

  f4 Ak0, Ak1, Aq0, Aq1, As; float Av;
  f4 Bk0, Bk1, Bq0, Bq1, Bs; float Bv;
  f4 Ck0, Ck1, Cq0, Cq1, Cs; float Cv;
  f4 Dk0, Dk1, Dq0, Dq1, Ds; float Dv;

#define GLK(P)                                                          \
  asm volatile(                                                         \
    "global_load_dwordx4 %0, %4, %5 offset:0\n\t"                       \
    "global_load_dwordx4 %1, %4, %5 offset:256\n\t"                     \
    "global_load_dwordx4 %2, %4, %6 offset:0\n\t"                       \
    "global_load_dwordx4 %3, %4, %6 offset:256"                         \
    : "=&v"(P##k0), "=&v"(P##k1), "=&v"(P##q0), "=&v"(P##q1)            \
    : "v"(voKQ), "s"(kbp), "s"(qbp));

#define GLVS(P)                                                         \
  asm volatile(                                                         \
    "global_load_dword %0, %2, %4\n\t"                                  \
    "global_load_dwordx4 %1, %3, %5"                                    \
    : "=&v"(P##v), "=&v"(P##s)                                          \
    : "v"(voV), "v"(voS), "s"(vbp), "s"(sbp));

#define ISSUE(P) GLK(P) GLVS(P)                                         \
  voKQ += 2048u; voV += 4096u; voS += 128u;

#define STORE(O)                                                        \
  { unsigned long long sv_;                                             \
    asm volatile("s_mov_b64 %0, exec\n\t"                               \
                 "s_mov_b64 exec, %1\n\t"                               \
                 "global_store_dword %2, %3, %4\n\t"                    \
                 "s_mov_b64 exec, %0"                                   \
                 : "=&s"(sv_)                                           \
                 : "s"(STMASK), "v"(voO), "v"(O), "s"(obp)              \
                 : "memory");                                           \
    voO += 4096u; }

#define WCNT_(N) asm volatile("s_waitcnt vmcnt(" #N ")" ::: "memory");  \
  __builtin_amdgcn_sched_barrier(0);
#define WCNT(N) WCNT_(N)

#define STEP(P, WN) { WCNT(WN)                                          \
  const float o_ = core_step(hs, P##k0, P##k1, P##q0, P##q1, P##v, P##s); \
  ISSUE(P) STORE(o_) }

#define STEPNL(P, WN) { WCNT(WN)                                        \
  const float o_ = core_step(hs, P##k0, P##k1, P##q0, P##q1, P##v, P##s); \
  STORE(o_) }

  // prologue: fill 4 slots (t = 0..3)
  ISSUE(A) ISSUE(B) ISSUE(C) ISSUE(D)

  // steps 0..3: waits 18/19/20/21 (prologue had no interleaved stores)
  STEP(A, 18) STEP(B, 19) STEP(C, 20) STEP(D, 21)

  // steady state: t = 4 .. 4091 (1022 x 4 steps), wait = 18 loads + 4 stores
  for (int it = 0; it < (Tn - 8) / 4; ++it) {
    STEP(A, 22) STEP(B, 22) STEP(C, 22) STEP(D, 22)
  }

  // epilogue: t = 4092..4095, no further loads; waits 22/16/10/4
  STEPNL(A, 22) STEPNL(B, 16) STEPNL(C, 10) STEPNL(D, 4)

#undef GLK
#undef GLVS
#undef ISSUE
#undef STORE
#undef WCNT_
#undef WCNT
#undef STEP
#undef STEPNL
}

extern "C" void kernel_launch(void* const* d_in, const int* in_sizes, int n_in,
                              void* d_out, int out_size, void* d_ws, size_t ws_size,
                              hipStream_t stream) {
  const float* A_log = (const float*)d_in[0];
  const float* a_in  = (const float*)d_in[1];
  const float* dtb   = (const float*)d_in[2];
  const float* q_in  = (const float*)d_in[3];
  const float* k_in  = (const float*)d_in[4];
  const float* v_in  = (const float*)d_in[5];
  const float* b_in  = (const float*)d_in[6];
  const float* h0    = (const float*)d_in[7];
  const int*   idx   = (const int*)d_in[8];
  float* out = (float*)d_out;
  float4* S  = (float4*)d_ws;     // B*T*HV float4 = 4 MB

  gdn_prepass<<<dim3(Bn * Tn / 4), dim3(256), 0, stream>>>(A_log, a_in, dtb,
                                                           q_in, k_in, b_in, S);
  gdn_recurrent<<<dim3(2048), dim3(64), 0, stream>>>(q_in, k_in, v_in, S,
                                                     h0, idx, out);
}